// Round 4
// baseline (408.220 us; speedup 1.0000x reference)
//
#include <hip/hip_runtime.h>
#include <stdint.h>

#define N_MEM    50000
#define DDIM     1024
#define MQ       256
#define NT       16                    // memory rows per chunk
#define NCHUNKS  (N_MEM / NT)          // 3125 exactly (no pad rows)
#define NBLOCKS  512
#define SIM_TH   0.6f
#define NEGINF   (-3.0e38f)

typedef __attribute__((ext_vector_type(4))) float f32x4;
typedef __attribute__((ext_vector_type(2))) long  lng2;

#if defined(__has_builtin)
#if __has_builtin(__builtin_amdgcn_cvt_pk_fp8_f32)
#define HAVE_CVT_PK_FP8 1
#endif
#endif

__device__ __forceinline__ unsigned int f2e4m3_1(float x) {
  unsigned int u = __float_as_uint(x);
  unsigned int s = (u >> 24) & 0x80u;
  unsigned int a = u & 0x7fffffffu;
  if (a >= 0x43E00000u) return s | 0x7Eu;
  if (a < 0x3C800000u) {
    float ax = __uint_as_float(a);
    unsigned int qq = (unsigned int)(ax * 512.0f + 0.5f);
    return s | qq;
  }
  a += 0x0007FFFFu + ((a >> 20) & 1u);
  int E = (int)(a >> 23) - 127 + 7;
  unsigned int m = (a >> 20) & 7u;
  if (E > 15 || (E == 15 && m == 7u)) return s | 0x7Eu;
  return s | ((unsigned int)E << 3) | m;
}

__device__ __forceinline__ unsigned int pack4_fp8(f32x4 v) {
#ifdef HAVE_CVT_PK_FP8
  int pk = __builtin_amdgcn_cvt_pk_fp8_f32(v.x, v.y, 0, false);
  pk = __builtin_amdgcn_cvt_pk_fp8_f32(v.z, v.w, pk, true);
  return (unsigned int)pk;
#else
  return f2e4m3_1(v.x) | (f2e4m3_1(v.y) << 8) |
         (f2e4m3_1(v.z) << 16) | (f2e4m3_1(v.w) << 24);
#endif
}

__device__ __forceinline__ long pack8_fp8(f32x4 a, f32x4 b) {
  return (long)pack4_fp8(a) | ((long)pack4_fp8(b) << 32);
}

// ---------------------------------------------------------------------------
// Kernel 0: query fp32 -> fp8 A-fragments, pre-arranged per (wave, kc2, lane).
// Frag slot for wave w, kc2, lane l=(q*16+li): 16 B =
//   bytes[0..8)  = A[m=16w+li][kc2*64 + q*8 .. +8)     (kc even)
//   bytes[8..16) = A[m=16w+li][kc2*64 + 32 + q*8 .. +8) (kc odd)
// Also qnorm[m].
// ---------------------------------------------------------------------------
__global__ __launch_bounds__(64) void prep_kernel(
    const float* __restrict__ q, unsigned char* __restrict__ qfrag,
    float* __restrict__ qnorm) {
  const int m = blockIdx.x;
  const int t = threadIdx.x;          // 0..63
  const int qq = t >> 4;              // 0..3
  const int kc2 = t & 15;             // 0..15
  const int w = m >> 4, li = m & 15;
  const float* row = q + (size_t)m * DDIM;

  f32x4 a0 = *(const f32x4*)(row + kc2 * 64 + qq * 8);
  f32x4 a1 = *(const f32x4*)(row + kc2 * 64 + qq * 8 + 4);
  f32x4 b0 = *(const f32x4*)(row + kc2 * 64 + 32 + qq * 8);
  f32x4 b1 = *(const f32x4*)(row + kc2 * 64 + 32 + qq * 8 + 4);

  lng2 frag;
  frag.x = pack8_fp8(a0, a1);
  frag.y = pack8_fp8(b0, b1);
  *(lng2*)(qfrag + (((size_t)w * 16 + kc2) * 64 + (qq * 16 + li)) * 16) = frag;

  float ss = a0.x*a0.x + a0.y*a0.y + a0.z*a0.z + a0.w*a0.w
           + a1.x*a1.x + a1.y*a1.y + a1.z*a1.z + a1.w*a1.w
           + b0.x*b0.x + b0.y*b0.y + b0.z*b0.z + b0.w*b0.w
           + b1.x*b1.x + b1.y*b1.y + b1.z*b1.z + b1.w*b1.w;
  #pragma unroll
  for (int off = 1; off < 64; off <<= 1) ss += __shfl_xor(ss, off);
  if (t == 0) qnorm[m] = sqrtf(ss);
}

// ---------------------------------------------------------------------------
// Kernel 1: persistent-A fused GEMM+argmax.
// 1024 threads = 16 waves; wave w owns query rows 16w..16w+15, A-frags in
// VGPRs (64/lane). B: 16-row x 1024 fp8 chunks, double-buffered LDS, staged
// via regs (fp32->fp8), prefetch distance = 1 chunk, ONE barrier per chunk.
// Compute reads are linear ds_read_b128 (conflict-free).
// ---------------------------------------------------------------------------
__global__ __launch_bounds__(1024, 4) void sim_kernel(
    const float* __restrict__ mem, const unsigned char* __restrict__ qfrag,
    float* __restrict__ pval, int* __restrict__ pidx) {
  __shared__ __align__(16) unsigned char Bs[2][NT * DDIM];  // 2 x 16 KB
  __shared__ float psum[2][NT][16];                         // 2 KB

  const int t = threadIdx.x;
  const int lane = t & 63;
  const int w = t >> 6;               // 0..15
  const int qq = lane >> 4;
  const int li = lane & 15;

  // ---- load A-frags once: 16 x 16 B per lane (coalesced 1 KB/wave/inst) ----
  lng2 areg[16];
  {
    const unsigned char* ab = qfrag + (size_t)w * 16384 + (size_t)lane * 16;
    #pragma unroll
    for (int k = 0; k < 16; ++k)
      areg[k] = *(const lng2*)(ab + k * 1024);
  }

  // staging geometry (fixed per thread): row srow, float cols scol..scol+15
  const int srow = li;                       // chunk-local row 0..15
  const int sq   = qq;                       // 0..3
  const int scol = (w * 4 + sq) * 16;
  // LDS frag dests for this thread's 16 bytes:
  const int qpA  = (sq & 1) * 2;
  const int half = sq >> 1;
  unsigned char* dst0base0 = &Bs[0][w * 1024 + (qpA * 16 + srow) * 16 + half * 8];
  unsigned char* dst0base1 = &Bs[1][w * 1024 + (qpA * 16 + srow) * 16 + half * 8];

  float best[4]; int bidx[4];
  #pragma unroll
  for (int r = 0; r < 4; ++r) { best[r] = NEGINF; bidx[r] = 0x7fffffff; }

  // ---- prologue: stage chunk c0 into buffer 0 ----
  int c = blockIdx.x;
  {
    const float* sp = mem + ((size_t)c * NT + srow) * DDIM + scol;
    f32x4 v0 = *(const f32x4*)(sp);
    f32x4 v1 = *(const f32x4*)(sp + 4);
    f32x4 v2 = *(const f32x4*)(sp + 8);
    f32x4 v3 = *(const f32x4*)(sp + 12);
    *(long*)(dst0base0)       = pack8_fp8(v0, v1);
    *(long*)(dst0base0 + 256) = pack8_fp8(v2, v3);
    float ss = v0.x*v0.x+v0.y*v0.y+v0.z*v0.z+v0.w*v0.w
             + v1.x*v1.x+v1.y*v1.y+v1.z*v1.z+v1.w*v1.w
             + v2.x*v2.x+v2.y*v2.y+v2.z*v2.z+v2.w*v2.w
             + v3.x*v3.x+v3.y*v3.y+v3.z*v3.z+v3.w*v3.w;
    ss += __shfl_xor(ss, 16);
    ss += __shfl_xor(ss, 32);
    if (lane < 16) psum[0][srow][w] = ss;
  }
  __syncthreads();

  int buf = 0;
  while (c < NCHUNKS) {
    const int cn = c + NBLOCKS;
    const bool have_next = (cn < NCHUNKS);

    // ---- issue next chunk's global loads NOW (consumed after compute) ----
    f32x4 v0, v1, v2, v3;
    if (have_next) {
      const float* sp = mem + ((size_t)cn * NT + srow) * DDIM + scol;
      v0 = *(const f32x4*)(sp);
      v1 = *(const f32x4*)(sp + 4);
      v2 = *(const f32x4*)(sp + 8);
      v3 = *(const f32x4*)(sp + 12);
    }

    // ---- compute chunk c: 16 x (ds_read_b128 + 2 MFMA), 2 acc chains ----
    f32x4 acc0 = (f32x4){0.f,0.f,0.f,0.f};
    f32x4 acc1 = (f32x4){0.f,0.f,0.f,0.f};
    const unsigned char* bb = &Bs[buf][lane * 16];
    #pragma unroll
    for (int k2 = 0; k2 < 16; ++k2) {
      lng2 bf = *(const lng2*)(bb + k2 * 1024);
      acc0 = __builtin_amdgcn_mfma_f32_16x16x32_fp8_fp8(areg[k2].x, bf.x, acc0, 0, 0, 0);
      acc1 = __builtin_amdgcn_mfma_f32_16x16x32_fp8_fp8(areg[k2].y, bf.y, acc1, 0, 0, 0);
    }

    // ---- finalize chunk c: rinv from psum, per-lane argmax update ----
    {
      float rs = 0.f;
      #pragma unroll
      for (int i = 0; i < 4; ++i) {
        f32x4 p = *(const f32x4*)(&psum[buf][li][i * 4]);
        rs += p.x + p.y + p.z + p.w;
      }
      const float rinv = (rs > 0.f) ? rsqrtf(rs) : 0.f;
      const int gn = c * NT + li;
      #pragma unroll
      for (int r = 0; r < 4; ++r) {
        const float vv = (acc0[r] + acc1[r]) * rinv;
        if (vv > best[r]) { best[r] = vv; bidx[r] = gn; }
      }
    }

    // ---- stage chunk cn into the other buffer ----
    if (have_next) {
      unsigned char* d = (buf ? dst0base0 : dst0base1);
      *(long*)(d)       = pack8_fp8(v0, v1);
      *(long*)(d + 256) = pack8_fp8(v2, v3);
      float ss = v0.x*v0.x+v0.y*v0.y+v0.z*v0.z+v0.w*v0.w
               + v1.x*v1.x+v1.y*v1.y+v1.z*v1.z+v1.w*v1.w
               + v2.x*v2.x+v2.y*v2.y+v2.z*v2.z+v2.w*v2.w
               + v3.x*v3.x+v3.y*v3.y+v3.z*v3.z+v3.w*v3.w;
      ss += __shfl_xor(ss, 16);
      ss += __shfl_xor(ss, 32);
      if (lane < 16) psum[buf ^ 1][srow][w] = ss;
    }
    __syncthreads();
    buf ^= 1;
    c = cn;
  }

  // ---- epilogue: reduce argmax across the 16 lanes of each quad-row ----
  #pragma unroll
  for (int r = 0; r < 4; ++r) {
    float b = best[r]; int i = bidx[r];
    #pragma unroll
    for (int off = 1; off < 16; off <<= 1) {
      const float ob = __shfl_xor(b, off);
      const int   oi = __shfl_xor(i, off);
      if (ob > b || (ob == b && oi < i)) { b = ob; i = oi; }
    }
    if (li == 0) {
      const int m = w * 16 + qq * 4 + r;
      pval[(size_t)blockIdx.x * MQ + m] = b;
      pidx[(size_t)blockIdx.x * MQ + m] = i;
    }
  }
}

// ---------------------------------------------------------------------------
// Kernel 2: global argmax over 512 block-partials, threshold, decode/zeros
// ---------------------------------------------------------------------------
__global__ __launch_bounds__(256) void finalize_kernel(
    const float* __restrict__ mem, const float* __restrict__ dec_w,
    const float* __restrict__ dec_b, const float* __restrict__ qnorm,
    const float* __restrict__ pval, const int* __restrict__ pidx,
    float* __restrict__ out) {
  const int b = blockIdx.x;
  const int t = threadIdx.x;
  float best = NEGINF; int bi = 0x7fffffff;
  for (int c = t; c < NBLOCKS; c += 256) {
    const float v = pval[(size_t)c * MQ + b];
    const int i = pidx[(size_t)c * MQ + b];
    if (v > best || (v == best && i < bi)) { best = v; bi = i; }
  }
  #pragma unroll
  for (int off = 1; off < 64; off <<= 1) {
    const float ov = __shfl_xor(best, off);
    const int oi = __shfl_xor(bi, off);
    if (ov > best || (ov == best && oi < bi)) { best = ov; bi = oi; }
  }
  __shared__ float sv[4]; __shared__ int si[4];
  __shared__ float sbest; __shared__ int sbi;
  if ((t & 63) == 0) { sv[t >> 6] = best; si[t >> 6] = bi; }
  __syncthreads();
  if (t == 0) {
    float bb = sv[0]; int ii = si[0];
    #pragma unroll
    for (int k = 1; k < 4; ++k)
      if (sv[k] > bb || (sv[k] == bb && si[k] < ii)) { bb = sv[k]; ii = si[k]; }
    sbest = bb; sbi = ii;
  }
  __syncthreads();

  const float sim = sbest / fmaxf(qnorm[b], 1e-20f);
  if (sim > SIM_TH) {
    __shared__ float ms[DDIM];
    *(f32x4*)(ms + t * 4) = *(const f32x4*)(mem + (size_t)sbi * DDIM + t * 4);
    __syncthreads();
    #pragma unroll
    for (int jj = 0; jj < 4; ++jj) {
      const int j = jj * 256 + t;
      const float* wr = dec_w + (size_t)j * DDIM;
      float s = dec_b[j];
      for (int k = 0; k < DDIM; k += 4) {
        const f32x4 a = *(const f32x4*)(ms + k);
        const f32x4 ww = *(const f32x4*)(wr + k);
        s += a.x * ww.x + a.y * ww.y + a.z * ww.z + a.w * ww.w;
      }
      out[(size_t)b * DDIM + j] = s;
    }
  } else {
    *(f32x4*)(out + (size_t)b * DDIM + t * 4) = (f32x4){0.f, 0.f, 0.f, 0.f};
  }
}

// ---------------------------------------------------------------------------
extern "C" void kernel_launch(void* const* d_in, const int* in_sizes, int n_in,
                              void* d_out, int out_size, void* d_ws, size_t ws_size,
                              hipStream_t stream) {
  const float* query = (const float*)d_in[0];   // [256,1024]
  const float* mem   = (const float*)d_in[1];   // [50000,1024]
  const float* dec_w = (const float*)d_in[2];   // [1024,1024]
  const float* dec_b = (const float*)d_in[3];   // [1024]
  float* out = (float*)d_out;                   // [256,1024]

  char* ws = (char*)d_ws;
  unsigned char* qfrag = (unsigned char*)ws;        // 256 KB
  float* qnorm = (float*)(ws + 262144);             // 1 KB
  float* pval  = (float*)(ws + 263168);             // 512 KB
  int*   pidx  = (int*)(ws + 263168 + (size_t)NBLOCKS * MQ * 4);

  hipLaunchKernelGGL(prep_kernel, dim3(MQ), dim3(64), 0, stream,
                     query, qfrag, qnorm);
  hipLaunchKernelGGL(sim_kernel, dim3(NBLOCKS), dim3(1024), 0, stream,
                     mem, qfrag, pval, pidx);
  hipLaunchKernelGGL(finalize_kernel, dim3(MQ), dim3(256), 0, stream,
                     mem, dec_w, dec_b, qnorm, pval, pidx, out);
}

// Round 5
// 291.176 us; speedup vs baseline: 1.4020x; 1.4020x over previous
//
#include <hip/hip_runtime.h>
#include <stdint.h>

#define N_MEM    50000
#define DDIM     1024
#define MQ       256
#define NT       16                    // memory rows per chunk
#define NCHUNKS  (N_MEM / NT)          // 3125 exactly
#define NBLOCKS  512
#define SIM_TH   0.6f
#define NEGINF   (-3.0e38f)

typedef __attribute__((ext_vector_type(4))) float f32x4;
typedef __attribute__((ext_vector_type(2))) long  lng2;

#if defined(__has_builtin)
#if __has_builtin(__builtin_amdgcn_cvt_pk_fp8_f32)
#define HAVE_CVT_PK_FP8 1
#endif
#endif

__device__ __forceinline__ unsigned int f2e4m3_1(float x) {
  unsigned int u = __float_as_uint(x);
  unsigned int s = (u >> 24) & 0x80u;
  unsigned int a = u & 0x7fffffffu;
  if (a >= 0x43E00000u) return s | 0x7Eu;
  if (a < 0x3C800000u) {
    float ax = __uint_as_float(a);
    unsigned int qq = (unsigned int)(ax * 512.0f + 0.5f);
    return s | qq;
  }
  a += 0x0007FFFFu + ((a >> 20) & 1u);
  int E = (int)(a >> 23) - 127 + 7;
  unsigned int m = (a >> 20) & 7u;
  if (E > 15 || (E == 15 && m == 7u)) return s | 0x7Eu;
  return s | ((unsigned int)E << 3) | m;
}

__device__ __forceinline__ unsigned int pack4_fp8(f32x4 v) {
#ifdef HAVE_CVT_PK_FP8
  int pk = __builtin_amdgcn_cvt_pk_fp8_f32(v.x, v.y, 0, false);
  pk = __builtin_amdgcn_cvt_pk_fp8_f32(v.z, v.w, pk, true);
  return (unsigned int)pk;
#else
  return f2e4m3_1(v.x) | (f2e4m3_1(v.y) << 8) |
         (f2e4m3_1(v.z) << 16) | (f2e4m3_1(v.w) << 24);
#endif
}

__device__ __forceinline__ long pack8_fp8(f32x4 a, f32x4 b) {
  return (long)pack4_fp8(a) | ((long)pack4_fp8(b) << 32);
}

// ---------------------------------------------------------------------------
// Kernel 0: query fp32 -> fp8 A-fragments (layout consumed by sim_kernel).
// Frag slot for wave w, k2, lane l=(q*16+li): 16 B =
//   bytes[0..8)  = A[m=16w+li][k2*64 + q*8 .. +8)
//   bytes[8..16) = A[m=16w+li][k2*64 + 32 + q*8 .. +8)
// ---------------------------------------------------------------------------
__global__ __launch_bounds__(64) void prep_kernel(
    const float* __restrict__ q, unsigned char* __restrict__ qfrag,
    float* __restrict__ qnorm) {
  const int m = blockIdx.x;
  const int t = threadIdx.x;          // 0..63
  const int qq = t >> 4;              // 0..3
  const int k2 = t & 15;              // 0..15
  const int w = m >> 4, li = m & 15;
  const float* row = q + (size_t)m * DDIM;

  f32x4 a0 = *(const f32x4*)(row + k2 * 64 + qq * 8);
  f32x4 a1 = *(const f32x4*)(row + k2 * 64 + qq * 8 + 4);
  f32x4 b0 = *(const f32x4*)(row + k2 * 64 + 32 + qq * 8);
  f32x4 b1 = *(const f32x4*)(row + k2 * 64 + 32 + qq * 8 + 4);

  lng2 frag;
  frag.x = pack8_fp8(a0, a1);
  frag.y = pack8_fp8(b0, b1);
  *(lng2*)(qfrag + (((size_t)w * 16 + k2) * 64 + (qq * 16 + li)) * 16) = frag;

  float ss = a0.x*a0.x + a0.y*a0.y + a0.z*a0.z + a0.w*a0.w
           + a1.x*a1.x + a1.y*a1.y + a1.z*a1.z + a1.w*a1.w
           + b0.x*b0.x + b0.y*b0.y + b0.z*b0.z + b0.w*b0.w
           + b1.x*b1.x + b1.y*b1.y + b1.z*b1.z + b1.w*b1.w;
  #pragma unroll
  for (int off = 1; off < 64; off <<= 1) ss += __shfl_xor(ss, off);
  if (t == 0) qnorm[m] = sqrtf(ss);
}

// ---------------------------------------------------------------------------
// Kernel 1: persistent-A fused GEMM+argmax.
// 16 waves; wave w owns query rows 16w..16w+15 (A in 64 VGPRs, full K).
// Wave w stages chunk-row w with LANE-CONTIGUOUS 16B nontemporal loads
// (1 KB/instruction coalesced, single-touch lines). fp8 frag-layout LDS,
// XOR-swizzled by k2&7 (writes 4-way, reads conflict-free). One barrier/chunk.
// ---------------------------------------------------------------------------
__global__ __launch_bounds__(1024, 4) void sim_kernel(
    const float* __restrict__ mem, const unsigned char* __restrict__ qfrag,
    float* __restrict__ pval, int* __restrict__ pidx) {
  __shared__ __align__(16) unsigned char Bs[2][NT * DDIM];  // 2 x 16 KB
  __shared__ float psum[2][NT];                             // per-row sumsq

  const int t = threadIdx.x;
  const int lane = t & 63;
  const int w = t >> 6;               // 0..15 (= chunk-local row staged)
  const int qq = lane >> 4;
  const int li = lane & 15;

  // ---- A-frags once: 16 x 16 B per lane ----
  lng2 areg[16];
  {
    const unsigned char* ab = qfrag + (size_t)w * 16384 + (size_t)lane * 16;
    #pragma unroll
    for (int k = 0; k < 16; ++k)
      areg[k] = *(const lng2*)(ab + k * 1024);
  }

  // ---- staging LDS offsets (compile-time per thread) ----
  // lane holds fp32 cols k = i*256 + lane*4 .. +4 of its wave's row (n = w):
  //   k2 = i*4 + (lane>>4); half=(lane>>3)&1; q=(lane>>1)&3; off=(lane&1)*4
  //   addr = k2*1024 + ((q*16 + w) ^ (k2&7))*16 + half*8 + off
  int soff[4];
  #pragma unroll
  for (int i = 0; i < 4; ++i) {
    const int k2 = i * 4 + (lane >> 4);
    const int unit = (((lane >> 1) & 3) * 16 + w) ^ (k2 & 7);
    soff[i] = k2 * 1024 + unit * 16 + ((lane >> 3) & 1) * 8 + (lane & 1) * 4;
  }

  float best[4]; int bidx[4];
  #pragma unroll
  for (int r = 0; r < 4; ++r) { best[r] = NEGINF; bidx[r] = 0x7fffffff; }

  // ---- prologue: stage chunk c0 into buffer 0 ----
  int c = blockIdx.x;
  {
    const float* gp = mem + ((size_t)c * NT + w) * DDIM + lane * 4;
    float ss = 0.f;
    #pragma unroll
    for (int i = 0; i < 4; ++i) {
      const f32x4 v = __builtin_nontemporal_load((const f32x4*)(gp + i * 256));
      ss += v.x*v.x + v.y*v.y + v.z*v.z + v.w*v.w;
      *(unsigned int*)(&Bs[0][soff[i]]) = pack4_fp8(v);
    }
    #pragma unroll
    for (int off = 1; off < 64; off <<= 1) ss += __shfl_xor(ss, off);
    if (lane == 0) psum[0][w] = ss;
  }
  __syncthreads();

  int buf = 0;
  while (c < NCHUNKS) {
    const int cn = c + NBLOCKS;
    const bool hn = (cn < NCHUNKS);

    // ---- issue next chunk's loads NOW (lane-contiguous, nontemporal) ----
    f32x4 v0, v1, v2, v3;
    if (hn) {
      const float* gp = mem + ((size_t)cn * NT + w) * DDIM + lane * 4;
      v0 = __builtin_nontemporal_load((const f32x4*)(gp));
      v1 = __builtin_nontemporal_load((const f32x4*)(gp + 256));
      v2 = __builtin_nontemporal_load((const f32x4*)(gp + 512));
      v3 = __builtin_nontemporal_load((const f32x4*)(gp + 768));
    }

    // ---- compute chunk c: 16 x (ds_read_b128 + 2 MFMA) ----
    f32x4 acc0 = (f32x4){0.f,0.f,0.f,0.f};
    f32x4 acc1 = (f32x4){0.f,0.f,0.f,0.f};
    const unsigned char* bbase = Bs[buf];
    #pragma unroll
    for (int k2 = 0; k2 < 16; ++k2) {
      lng2 bf = *(const lng2*)(bbase + k2 * 1024 + ((lane ^ (k2 & 7)) << 4));
      acc0 = __builtin_amdgcn_mfma_f32_16x16x32_fp8_fp8(areg[k2].x, bf.x, acc0, 0, 0, 0);
      acc1 = __builtin_amdgcn_mfma_f32_16x16x32_fp8_fp8(areg[k2].y, bf.y, acc1, 0, 0, 0);
    }

    // ---- argmax for chunk c ----
    {
      const float rs = psum[buf][li];
      const float rinv = (rs > 0.f) ? rsqrtf(rs) : 0.f;
      const int gn = c * NT + li;
      #pragma unroll
      for (int r = 0; r < 4; ++r) {
        const float vv = (acc0[r] + acc1[r]) * rinv;
        if (vv > best[r]) { best[r] = vv; bidx[r] = gn; }
      }
    }

    // ---- stage chunk cn into the other buffer ----
    if (hn) {
      unsigned char* d = Bs[buf ^ 1];
      float ss = v0.x*v0.x+v0.y*v0.y+v0.z*v0.z+v0.w*v0.w;
      *(unsigned int*)(d + soff[0]) = pack4_fp8(v0);
      ss += v1.x*v1.x+v1.y*v1.y+v1.z*v1.z+v1.w*v1.w;
      *(unsigned int*)(d + soff[1]) = pack4_fp8(v1);
      ss += v2.x*v2.x+v2.y*v2.y+v2.z*v2.z+v2.w*v2.w;
      *(unsigned int*)(d + soff[2]) = pack4_fp8(v2);
      ss += v3.x*v3.x+v3.y*v3.y+v3.z*v3.z+v3.w*v3.w;
      *(unsigned int*)(d + soff[3]) = pack4_fp8(v3);
      #pragma unroll
      for (int off = 1; off < 64; off <<= 1) ss += __shfl_xor(ss, off);
      if (lane == 0) psum[buf ^ 1][w] = ss;
    }
    __syncthreads();
    buf ^= 1;
    c = cn;
  }

  // ---- epilogue: reduce argmax across the 16 lanes of each quad-row ----
  #pragma unroll
  for (int r = 0; r < 4; ++r) {
    float b = best[r]; int i = bidx[r];
    #pragma unroll
    for (int off = 1; off < 16; off <<= 1) {
      const float ob = __shfl_xor(b, off);
      const int   oi = __shfl_xor(i, off);
      if (ob > b || (ob == b && oi < i)) { b = ob; i = oi; }
    }
    if (li == 0) {
      const int m = w * 16 + qq * 4 + r;
      pval[(size_t)blockIdx.x * MQ + m] = b;
      pidx[(size_t)blockIdx.x * MQ + m] = i;
    }
  }
}

// ---------------------------------------------------------------------------
// Kernel 2: global argmax over 512 block-partials, threshold, decode/zeros
// ---------------------------------------------------------------------------
__global__ __launch_bounds__(256) void finalize_kernel(
    const float* __restrict__ mem, const float* __restrict__ dec_w,
    const float* __restrict__ dec_b, const float* __restrict__ qnorm,
    const float* __restrict__ pval, const int* __restrict__ pidx,
    float* __restrict__ out) {
  const int b = blockIdx.x;
  const int t = threadIdx.x;
  float best = NEGINF; int bi = 0x7fffffff;
  for (int c = t; c < NBLOCKS; c += 256) {
    const float v = pval[(size_t)c * MQ + b];
    const int i = pidx[(size_t)c * MQ + b];
    if (v > best || (v == best && i < bi)) { best = v; bi = i; }
  }
  #pragma unroll
  for (int off = 1; off < 64; off <<= 1) {
    const float ov = __shfl_xor(best, off);
    const int oi = __shfl_xor(bi, off);
    if (ov > best || (ov == best && oi < bi)) { best = ov; bi = oi; }
  }
  __shared__ float sv[4]; __shared__ int si[4];
  __shared__ float sbest; __shared__ int sbi;
  if ((t & 63) == 0) { sv[t >> 6] = best; si[t >> 6] = bi; }
  __syncthreads();
  if (t == 0) {
    float bb = sv[0]; int ii = si[0];
    #pragma unroll
    for (int k = 1; k < 4; ++k)
      if (sv[k] > bb || (sv[k] == bb && si[k] < ii)) { bb = sv[k]; ii = si[k]; }
    sbest = bb; sbi = ii;
  }
  __syncthreads();

  const float sim = sbest / fmaxf(qnorm[b], 1e-20f);
  if (sim > SIM_TH) {
    __shared__ float ms[DDIM];
    *(f32x4*)(ms + t * 4) = *(const f32x4*)(mem + (size_t)sbi * DDIM + t * 4);
    __syncthreads();
    #pragma unroll
    for (int jj = 0; jj < 4; ++jj) {
      const int j = jj * 256 + t;
      const float* wr = dec_w + (size_t)j * DDIM;
      float s = dec_b[j];
      for (int k = 0; k < DDIM; k += 4) {
        const f32x4 a = *(const f32x4*)(ms + k);
        const f32x4 ww = *(const f32x4*)(wr + k);
        s += a.x * ww.x + a.y * ww.y + a.z * ww.z + a.w * ww.w;
      }
      out[(size_t)b * DDIM + j] = s;
    }
  } else {
    *(f32x4*)(out + (size_t)b * DDIM + t * 4) = (f32x4){0.f, 0.f, 0.f, 0.f};
  }
}

// ---------------------------------------------------------------------------
extern "C" void kernel_launch(void* const* d_in, const int* in_sizes, int n_in,
                              void* d_out, int out_size, void* d_ws, size_t ws_size,
                              hipStream_t stream) {
  const float* query = (const float*)d_in[0];   // [256,1024]
  const float* mem   = (const float*)d_in[1];   // [50000,1024]
  const float* dec_w = (const float*)d_in[2];   // [1024,1024]
  const float* dec_b = (const float*)d_in[3];   // [1024]
  float* out = (float*)d_out;                   // [256,1024]

  char* ws = (char*)d_ws;
  unsigned char* qfrag = (unsigned char*)ws;        // 256 KB
  float* qnorm = (float*)(ws + 262144);             // 1 KB
  float* pval  = (float*)(ws + 263168);             // 512 KB
  int*   pidx  = (int*)(ws + 263168 + (size_t)NBLOCKS * MQ * 4);

  hipLaunchKernelGGL(prep_kernel, dim3(MQ), dim3(64), 0, stream,
                     query, qfrag, qnorm);
  hipLaunchKernelGGL(sim_kernel, dim3(NBLOCKS), dim3(1024), 0, stream,
                     mem, qfrag, pval, pidx);
  hipLaunchKernelGGL(finalize_kernel, dim3(MQ), dim3(256), 0, stream,
                     mem, dec_w, dec_b, qnorm, pval, pidx, out);
}